// Round 9
// baseline (306.261 us; speedup 1.0000x reference)
//
#include <hip/hip_runtime.h>
#include <stdint.h>

// BitNetLinear eval forward on MI355X (gfx950).
// M = B*S = 32768, K = 1024 (in_features), N = 1024 (out_features).
//
// R8: fused quant-A + GEMM, fixing R5/R7's measured defects:
//   - M=64 rows/block (R5's B-amortization; R7's M=32 doubled bf traffic)
//   - 512 thr / 8 waves; wave = 64 rows x 128 cols (4 chunks of 32):
//     acc[4][2]=32 AGPR, bf[3][2]=24, af[4]=16 -> ~90 regs, no R6 spill
//   - bf prefetch distance 2 (3 rotating buffers) covers L2/L3 latency
//   - 16 K-bodies macro-unrolled -> all reg indices static (rule #20)
// qa = 64 KB -> 2 blocks/CU -> 16 waves/CU (4/SIMD).

#define MK_M 32768
#define MK_K 1024
#define MK_N 1024

typedef __attribute__((ext_vector_type(4))) int int32x4;

// ---- workspace layout ----
#define WS_MAXP_OFF 64
#define WS_PART_OFF 8448
#define WS_QW_OFF 16384
#define WS_NEEDED (WS_QW_OFF + (1 << 20))

// fused: blocks [0,2048) -> per-block max|x|; blocks [2048,2112) -> partial sum|W|
__global__ void kprep(const float4* __restrict__ x4, const float4* __restrict__ w4,
                      float* __restrict__ maxp, double* __restrict__ partials, long n4x) {
    const int bid = blockIdx.x;
    if (bid < 2048) {
        float m = 0.f;
        const long stride = 2048L * 256;
        for (long i = (long)bid * 256 + threadIdx.x; i < n4x; i += stride) {
            float4 v = x4[i];
            m = fmaxf(m, fmaxf(fmaxf(fabsf(v.x), fabsf(v.y)), fmaxf(fabsf(v.z), fabsf(v.w))));
        }
        #pragma unroll
        for (int off = 1; off < 64; off <<= 1) m = fmaxf(m, __shfl_xor(m, off));
        __shared__ float sm[4];
        int lane = threadIdx.x & 63, wid = threadIdx.x >> 6;
        if (lane == 0) sm[wid] = m;
        __syncthreads();
        if (threadIdx.x == 0) maxp[bid] = fmaxf(fmaxf(sm[0], sm[1]), fmaxf(sm[2], sm[3]));
    } else {
        double s = 0.0;
        for (int i = (bid - 2048) * 256 + threadIdx.x; i < (1 << 18); i += 64 * 256) {
            float4 v = w4[i];
            s += (double)fabsf(v.x);
            s += (double)fabsf(v.y);
            s += (double)fabsf(v.z);
            s += (double)fabsf(v.w);
        }
        __shared__ double sd[256];
        sd[threadIdx.x] = s;
        __syncthreads();
        for (int h = 128; h > 0; h >>= 1) {
            if ((int)threadIdx.x < h) sd[threadIdx.x] += sd[threadIdx.x + h];
            __syncthreads();
        }
        if (threadIdx.x == 0) partials[bid - 2048] = sd[0];
    }
}

// every block redundantly reduces partials[64] in the SAME fixed order.
__global__ void kquant_w(const float4* __restrict__ w4, unsigned* __restrict__ qw,
                         const double* __restrict__ partials, float* __restrict__ wscp) {
    __shared__ double sws;
    if (threadIdx.x < 64) {
        double s = partials[threadIdx.x];
        #pragma unroll
        for (int off = 1; off < 64; off <<= 1) s += __shfl_xor(s, off);
        if (threadIdx.x == 0) sws = s;
    }
    __syncthreads();
    float wsc = (float)(sws / 1048576.0);   // mean|W| over 2^20 elements
    if (blockIdx.x == 0 && threadIdx.x == 0) *wscp = wsc;
    float thr = 0.5f * wsc;
    int stride = gridDim.x * blockDim.x;
    for (int i = blockIdx.x * blockDim.x + threadIdx.x; i < (1 << 18); i += stride) {
        float4 v = w4[i];
        int q0 = (fabsf(v.x) > thr) ? (v.x > 0.f ? 1 : -1) : 0;
        int q1 = (fabsf(v.y) > thr) ? (v.y > 0.f ? 1 : -1) : 0;
        int q2 = (fabsf(v.z) > thr) ? (v.z > 0.f ? 1 : -1) : 0;
        int q3 = (fabsf(v.w) > thr) ? (v.w > 0.f ? 1 : -1) : 0;
        qw[i] = (q0 & 0xff) | ((q1 & 0xff) << 8) | ((q2 & 0xff) << 16) | ((q3 & 0xff) << 24);
    }
}

// ---- fused quant-A + int8 GEMM ----
__global__ __launch_bounds__(512, 4) void kfused(
    const float* __restrict__ x, const char* __restrict__ qw,
    const float* __restrict__ bias, const float* __restrict__ wscp,
    const float* __restrict__ maxp, float* __restrict__ out)
{
    __shared__ __align__(16) char qa[64 * 1024];
    __shared__ float sm[8];

    const int t = threadIdx.x;
    const int l = t & 63;
    const int w = t >> 6;          // 0..7
    const long m0 = (long)blockIdx.x * 64;

    // i_scale: redundant deterministic reduce of maxp[2048]
    float m = 0.f;
    #pragma unroll
    for (int j = 0; j < 4; ++j) m = fmaxf(m, maxp[t + 512 * j]);
    #pragma unroll
    for (int off = 1; off < 64; off <<= 1) m = fmaxf(m, __shfl_xor(m, off));
    if (l == 0) sm[w] = m;
    __syncthreads();
    float mm = fmaxf(fmaxf(fmaxf(sm[0], sm[1]), fmaxf(sm[2], sm[3])),
                     fmaxf(fmaxf(sm[4], sm[5]), fmaxf(sm[6], sm[7])));
    const float isc = mm / 127.0f;
    const float rin = 1.0f / isc;  // reciprocal-mul quant (absmax 0.0 in R5-R7)

    // Phase A: wave w quantizes rows w*8..w*8+7 into qa with 16B-chunk XOR
    // swizzle (chunk' = chunk ^ (row&7)). Verified bit-identical R5-R7.
    #pragma unroll
    for (int j = 0; j < 8; ++j) {
        const int row = w * 8 + j;
        const float4* src = (const float4*)(x + (m0 + row) * MK_K);
        #pragma unroll
        for (int e = 0; e < 4; ++e) {
            float4 v = src[e * 64 + l];
            int i0 = (int)fminf(fmaxf(rintf(v.x * rin), -128.f), 127.f);
            int i1 = (int)fminf(fmaxf(rintf(v.y * rin), -128.f), 127.f);
            int i2 = (int)fminf(fmaxf(rintf(v.z * rin), -128.f), 127.f);
            int i3 = (int)fminf(fmaxf(rintf(v.w * rin), -128.f), 127.f);
            unsigned pk = (i0 & 0xff) | ((i1 & 0xff) << 8) | ((i2 & 0xff) << 16) | ((i3 & 0xff) << 24);
            const int d = e * 64 + l;
            const int dsw = ((((d >> 2) ^ (row & 7)) << 2) | (d & 3));
            *(unsigned*)(qa + row * 1024 + dsw * 4) = pk;
        }
    }
    __syncthreads();

    // Phase B: barrier-free. Wave w covers cols [w*128, w*128+128) as 4
    // chunks of 32. Per body: 4 ds_read_b128 (af, all 64 rows), 2 global
    // bf loads (distance-2 prefetch into 3 rotating buffers), 8 MFMAs.
    const float wsc = *wscp;
    const int crow = (l >> 4) * 4;
    const int ccol = l & 15;
    // af chunk-XOR is row&7 = l&7 (mi*16 keeps bit pattern): same for all mi.
    const int axor = l & 7;
    const int arow = l & 15;

    for (int nc = 0; nc < 4; ++nc) {
        const int nb = w * 128 + nc * 32;
        const char* bq = qw + (long)(nb + (l & 15)) * MK_K + (l >> 4) * 16;

        int32x4 acc[4][2];
        #pragma unroll
        for (int mi = 0; mi < 4; ++mi) {
            acc[mi][0] = (int32x4)0;
            acc[mi][1] = (int32x4)0;
        }

        int32x4 bf0[2], bf1[2], bf2[2];
        // prologue: kt=0 -> bf0, kt=1 -> bf1 (distance-2 queue primed)
        bf0[0] = *(const int32x4*)(bq);
        bf0[1] = *(const int32x4*)(bq + 16 * MK_K);
        bf1[0] = *(const int32x4*)(bq + 64);
        bf1[1] = *(const int32x4*)(bq + 16 * MK_K + 64);

#define R8_BODY(KT, BC, BN)                                                       \
        {                                                                         \
            const int cc = ((KT) * 4 + (l >> 4)) ^ axor;                          \
            int32x4 af0 = *(const int32x4*)(qa + (arow)      * 1024 + cc * 16);   \
            int32x4 af1 = *(const int32x4*)(qa + (arow + 16) * 1024 + cc * 16);   \
            int32x4 af2 = *(const int32x4*)(qa + (arow + 32) * 1024 + cc * 16);   \
            int32x4 af3 = *(const int32x4*)(qa + (arow + 48) * 1024 + cc * 16);   \
            if ((KT) < 14) {                                                      \
                BN[0] = *(const int32x4*)(bq + ((KT) + 2) * 64);                  \
                BN[1] = *(const int32x4*)(bq + 16 * MK_K + ((KT) + 2) * 64);      \
            }                                                                     \
            acc[0][0] = __builtin_amdgcn_mfma_i32_16x16x64_i8(af0, BC[0], acc[0][0], 0, 0, 0); \
            acc[0][1] = __builtin_amdgcn_mfma_i32_16x16x64_i8(af0, BC[1], acc[0][1], 0, 0, 0); \
            acc[1][0] = __builtin_amdgcn_mfma_i32_16x16x64_i8(af1, BC[0], acc[1][0], 0, 0, 0); \
            acc[1][1] = __builtin_amdgcn_mfma_i32_16x16x64_i8(af1, BC[1], acc[1][1], 0, 0, 0); \
            acc[2][0] = __builtin_amdgcn_mfma_i32_16x16x64_i8(af2, BC[0], acc[2][0], 0, 0, 0); \
            acc[2][1] = __builtin_amdgcn_mfma_i32_16x16x64_i8(af2, BC[1], acc[2][1], 0, 0, 0); \
            acc[3][0] = __builtin_amdgcn_mfma_i32_16x16x64_i8(af3, BC[0], acc[3][0], 0, 0, 0); \
            acc[3][1] = __builtin_amdgcn_mfma_i32_16x16x64_i8(af3, BC[1], acc[3][1], 0, 0, 0); \
        }

        R8_BODY(0,  bf0, bf2)
        R8_BODY(1,  bf1, bf0)
        R8_BODY(2,  bf2, bf1)
        R8_BODY(3,  bf0, bf2)
        R8_BODY(4,  bf1, bf0)
        R8_BODY(5,  bf2, bf1)
        R8_BODY(6,  bf0, bf2)
        R8_BODY(7,  bf1, bf0)
        R8_BODY(8,  bf2, bf1)
        R8_BODY(9,  bf0, bf2)
        R8_BODY(10, bf1, bf0)
        R8_BODY(11, bf2, bf1)
        R8_BODY(12, bf0, bf2)
        R8_BODY(13, bf1, bf0)
        R8_BODY(14, bf2, bf1)
        R8_BODY(15, bf0, bf2)
#undef R8_BODY

        // epilogue: C/D layout col = lane&15, row = (lane>>4)*4 + reg (verified)
        #pragma unroll
        for (int mi = 0; mi < 4; ++mi) {
            #pragma unroll
            for (int ni = 0; ni < 2; ++ni) {
                long r0 = m0 + mi * 16 + crow;
                int c = nb + ni * 16 + ccol;
                float b = bias[c];
                #pragma unroll
                for (int j = 0; j < 4; ++j) {
                    out[(r0 + j) * MK_N + c] = ((float)acc[mi][ni][j] * wsc) * isc + b;
                }
            }
        }
    }
}

extern "C" void kernel_launch(void* const* d_in, const int* in_sizes, int n_in,
                              void* d_out, int out_size, void* d_ws, size_t ws_size,
                              hipStream_t stream) {
    const float* x = (const float*)d_in[0];
    const float* wt = (const float*)d_in[1];
    const float* bias = (const float*)d_in[2];
    float* out = (float*)d_out;

    if (ws_size < WS_NEEDED) return;

    char* ws = (char*)d_ws;
    float* wscp = (float*)(ws + 0);
    float* maxp = (float*)(ws + WS_MAXP_OFF);
    double* partials = (double*)(ws + WS_PART_OFF);
    char* qw = ws + WS_QW_OFF;

    const long n_x = (long)in_sizes[0];   // 33554432
    const long n4_x = n_x >> 2;

    kprep<<<2112, 256, 0, stream>>>((const float4*)x, (const float4*)wt, maxp, partials, n4_x);
    kquant_w<<<256, 256, 0, stream>>>((const float4*)wt, (unsigned*)qw, partials, wscp);
    kfused<<<MK_M / 64, 512, 0, stream>>>(x, qw, bias, wscp, maxp, out);
}

// Round 10
// 114.173 us; speedup vs baseline: 2.6824x; 2.6824x over previous
//
#include <hip/hip_runtime.h>
#include <stdint.h>

// BitNetLinear eval forward on MI355X (gfx950).
// M = B*S = 32768, K = 1024 (in_features), N = 1024 (out_features).
//
// R9: revert to the best-measured pipeline (R2/R4, ~110us) and apply one
// lever to kgemm: 2-phase MFMA/ds/stage interleave per K-tile (T3/T5 with
// 16-MFMA clusters; R1's failed 4-phase had 8-MFMA clusters + extra ds).
// Non-GEMM kernels byte-identical to R4. kgemm geometry/swizzle/vmcnt
// byte-identical to R2 except the phase split.

#define MK_M 32768
#define MK_K 1024
#define MK_N 1024

typedef __attribute__((ext_vector_type(4))) int int32x4;

// ---- workspace layout ----
#define WS_MAXP_OFF 64
#define WS_PART_OFF 8448
#define WS_QW_OFF 16384
#define WS_QX_OFF (16384 + (1 << 20))
#define WS_NEEDED (WS_QX_OFF + (size_t)MK_M * MK_K)

// fused: blocks [0,2048) -> per-block max|x|; blocks [2048,2112) -> partial sum|W|
__global__ void kprep(const float4* __restrict__ x4, const float4* __restrict__ w4,
                      float* __restrict__ maxp, double* __restrict__ partials, long n4x) {
    const int bid = blockIdx.x;
    if (bid < 2048) {
        float m = 0.f;
        const long stride = 2048L * 256;
        for (long i = (long)bid * 256 + threadIdx.x; i < n4x; i += stride) {
            float4 v = x4[i];
            m = fmaxf(m, fmaxf(fmaxf(fabsf(v.x), fabsf(v.y)), fmaxf(fabsf(v.z), fabsf(v.w))));
        }
        #pragma unroll
        for (int off = 1; off < 64; off <<= 1) m = fmaxf(m, __shfl_xor(m, off));
        __shared__ float sm[4];
        int lane = threadIdx.x & 63, wid = threadIdx.x >> 6;
        if (lane == 0) sm[wid] = m;
        __syncthreads();
        if (threadIdx.x == 0) maxp[bid] = fmaxf(fmaxf(sm[0], sm[1]), fmaxf(sm[2], sm[3]));
    } else {
        double s = 0.0;
        for (int i = (bid - 2048) * 256 + threadIdx.x; i < (1 << 18); i += 64 * 256) {
            float4 v = w4[i];
            s += (double)fabsf(v.x);
            s += (double)fabsf(v.y);
            s += (double)fabsf(v.z);
            s += (double)fabsf(v.w);
        }
        __shared__ double sd[256];
        sd[threadIdx.x] = s;
        __syncthreads();
        for (int h = 128; h > 0; h >>= 1) {
            if ((int)threadIdx.x < h) sd[threadIdx.x] += sd[threadIdx.x + h];
            __syncthreads();
        }
        if (threadIdx.x == 0) partials[bid - 2048] = sd[0];
    }
}

// every block redundantly reduces partials[64] in the SAME fixed order.
__global__ void kquant_w(const float4* __restrict__ w4, unsigned* __restrict__ qw,
                         const double* __restrict__ partials, float* __restrict__ wscp) {
    __shared__ double sws;
    if (threadIdx.x < 64) {
        double s = partials[threadIdx.x];
        #pragma unroll
        for (int off = 1; off < 64; off <<= 1) s += __shfl_xor(s, off);
        if (threadIdx.x == 0) sws = s;
    }
    __syncthreads();
    float wsc = (float)(sws / 1048576.0);   // mean|W| over 2^20 elements
    if (blockIdx.x == 0 && threadIdx.x == 0) *wscp = wsc;
    float thr = 0.5f * wsc;
    int stride = gridDim.x * blockDim.x;
    for (int i = blockIdx.x * blockDim.x + threadIdx.x; i < (1 << 18); i += stride) {
        float4 v = w4[i];
        int q0 = (fabsf(v.x) > thr) ? (v.x > 0.f ? 1 : -1) : 0;
        int q1 = (fabsf(v.y) > thr) ? (v.y > 0.f ? 1 : -1) : 0;
        int q2 = (fabsf(v.z) > thr) ? (v.z > 0.f ? 1 : -1) : 0;
        int q3 = (fabsf(v.w) > thr) ? (v.w > 0.f ? 1 : -1) : 0;
        qw[i] = (q0 & 0xff) | ((q1 & 0xff) << 8) | ((q2 & 0xff) << 16) | ((q3 & 0xff) << 24);
    }
}

// every block redundantly reduces maxp[2048] (max is order-independent).
__global__ void kquant_x(const float4* __restrict__ x4, unsigned* __restrict__ qx,
                         const float* __restrict__ maxp, float* __restrict__ iscp, long n4) {
    float m = 0.f;
    #pragma unroll
    for (int j = 0; j < 8; ++j) m = fmaxf(m, maxp[threadIdx.x + 256 * j]);
    #pragma unroll
    for (int off = 1; off < 64; off <<= 1) m = fmaxf(m, __shfl_xor(m, off));
    __shared__ float sm[4];
    int lane = threadIdx.x & 63, wid = threadIdx.x >> 6;
    if (lane == 0) sm[wid] = m;
    __syncthreads();
    float isc = fmaxf(fmaxf(sm[0], sm[1]), fmaxf(sm[2], sm[3])) / 127.0f;  // fp32 div
    if (blockIdx.x == 0 && threadIdx.x == 0) *iscp = isc;
    long stride = (long)gridDim.x * blockDim.x;
    for (long i = (long)blockIdx.x * blockDim.x + threadIdx.x; i < n4; i += stride) {
        float4 v = x4[i];
        // IEEE divide + rint (half-to-even) to match jnp.round(x / i_scale)
        float q0 = fminf(fmaxf(rintf(v.x / isc), -128.f), 127.f);
        float q1 = fminf(fmaxf(rintf(v.y / isc), -128.f), 127.f);
        float q2 = fminf(fmaxf(rintf(v.z / isc), -128.f), 127.f);
        float q3 = fminf(fmaxf(rintf(v.w / isc), -128.f), 127.f);
        int i0 = (int)q0, i1 = (int)q1, i2 = (int)q2, i3 = (int)q3;
        qx[i] = (i0 & 0xff) | ((i1 & 0xff) << 8) | ((i2 & 0xff) << 16) | ((i3 & 0xff) << 24);
    }
}

// ---- int8 GEMM: out[m][n] = sum_k qx[m][k] * qw[n][k] ----
// 256x256 tile, BK=64, 8 waves (2Mx4N), per-wave 128x64 (acc 8x4 frags).
// Triple-buffered LDS (96 KB), depth-2 stage, counted vmcnt(4) at tile top
// (all R2-proven). NEW: each K-tile's 32 MFMAs split into 2 phases of 16
// with barrier pairs + setprio; each phase loads its af half (4 ds_read)
// + bf[4] (re-read in ph1, conflict-free swizzle) and issues 2 stage units.
__global__ __launch_bounds__(512, 2) void kgemm(
    const char* __restrict__ qx, const char* __restrict__ qw,
    const float* __restrict__ bias, const float* __restrict__ wscp,
    const float* __restrict__ iscp, float* __restrict__ out)
{
    __shared__ __align__(16) char smem[3 * 32768];

    const int t = threadIdx.x;
    const int l = t & 63;
    const int w = t >> 6;          // 0..7
    const int wm = w >> 2;         // 0..1  (M half)
    const int wn = w & 3;          // 0..3  (N quarter)

    // XCD-bijective swizzle: 512 blocks, 8 XCDs, 64 contiguous per XCD.
    const int bid = blockIdx.x;
    const int wg = (bid & 7) * 64 + (bid >> 3);
    const int tm = wg >> 2, tn = wg & 3;
    const long m0 = (long)tm * 256;
    const int n0 = tn * 256;

    // staging constants: unit = 128 rows x 64B = 8KB = 512 threads x 16B
    const int grow = t >> 2;
    const int gch = (t & 3) ^ ((t >> 3) & 3);   // pre-swizzled global chunk
    const long goff = (long)grow * MK_K + gch * 16;
    const int loff = t * 16;

    const char* gAt = qx + m0 * MK_K + goff;
    const char* gBt = qw + (long)n0 * MK_K + goff;

    int32x4 acc[8][4];
    #pragma unroll
    for (int mi = 0; mi < 8; ++mi)
        #pragma unroll
        for (int ni = 0; ni < 4; ++ni) acc[mi][ni] = (int32x4)0;

    auto stage = [&](int u, int kt, int b) {
        char* nbase = smem + b * 32768;
        const char* src;
        char* dst;
        if (u < 2) {
            src = gAt + (long)u * 128 * MK_K + kt * 64;
            dst = nbase + u * 8192 + loff;
        } else {
            src = gBt + (long)(u - 2) * 128 * MK_K + kt * 64;
            dst = nbase + 16384 + (u - 2) * 8192 + loff;
        }
        __builtin_amdgcn_global_load_lds(
            (const __attribute__((address_space(1))) void*)src,
            (__attribute__((address_space(3))) void*)dst, 16, 0, 0);
    };

    // prologue: tiles 0 and 1 into buffers 0 and 1 (8 loads in flight)
    #pragma unroll
    for (int u = 0; u < 4; ++u) stage(u, 0, 0);
    #pragma unroll
    for (int u = 0; u < 4; ++u) stage(u, 1, 1);

    for (int kt = 0; kt < 16; ++kt) {
        // wait for tile kt's 4 units; keep tile kt+1's 4 in flight (T4).
        if (kt < 15) asm volatile("s_waitcnt vmcnt(4)" ::: "memory");
        else         asm volatile("s_waitcnt vmcnt(0)" ::: "memory");
        __builtin_amdgcn_s_barrier();
        // buffer (kt+2)%3 == (kt-1)%3 fully consumed by barrier (R2-proven).

        const int cb = kt % 3;
        const int nb = (kt + 2) % 3;
        const char* bufA = smem + cb * 32768;
        const char* bufB = bufA + 16384;
        const bool do_stage = (kt < 14);

        #pragma unroll
        for (int ph = 0; ph < 2; ++ph) {
            int32x4 af[4], bf[4];
            #pragma unroll
            for (int i = 0; i < 4; ++i) {
                int row = wm * 128 + (ph * 4 + i) * 16 + (l & 15);
                int ch = (l >> 4) ^ ((row >> 1) & 3);
                af[i] = *(const int32x4*)(bufA + row * 64 + ch * 16);
            }
            #pragma unroll
            for (int i = 0; i < 4; ++i) {
                int row = wn * 64 + i * 16 + (l & 15);
                int ch = (l >> 4) ^ ((row >> 1) & 3);
                bf[i] = *(const int32x4*)(bufB + row * 64 + ch * 16);
            }
            if (do_stage) {
                stage(ph * 2 + 0, kt + 2, nb);
                stage(ph * 2 + 1, kt + 2, nb);
            }
            __builtin_amdgcn_s_barrier();
            __builtin_amdgcn_s_setprio(1);
            #pragma unroll
            for (int mi = 0; mi < 4; ++mi)
                #pragma unroll
                for (int ni = 0; ni < 4; ++ni)
                    acc[ph * 4 + mi][ni] = __builtin_amdgcn_mfma_i32_16x16x64_i8(
                        af[mi], bf[ni], acc[ph * 4 + mi][ni], 0, 0, 0);
            __builtin_amdgcn_s_setprio(0);
            __builtin_amdgcn_s_barrier();
        }
    }

    // epilogue: C/D layout col = lane&15, row = (lane>>4)*4 + reg (verified)
    const float wsc = *wscp, isc = *iscp;
    const int crow = (l >> 4) * 4;
    const int ccol = l & 15;
    #pragma unroll
    for (int mi = 0; mi < 8; ++mi) {
        #pragma unroll
        for (int ni = 0; ni < 4; ++ni) {
            long r0 = m0 + wm * 128 + mi * 16 + crow;
            int c = n0 + wn * 64 + ni * 16 + ccol;
            float b = bias[c];
            #pragma unroll
            for (int j = 0; j < 4; ++j) {
                out[(r0 + j) * MK_N + c] = ((float)acc[mi][ni][j] * wsc) * isc + b;
            }
        }
    }
}

extern "C" void kernel_launch(void* const* d_in, const int* in_sizes, int n_in,
                              void* d_out, int out_size, void* d_ws, size_t ws_size,
                              hipStream_t stream) {
    const float* x = (const float*)d_in[0];
    const float* wt = (const float*)d_in[1];
    const float* bias = (const float*)d_in[2];
    float* out = (float*)d_out;

    if (ws_size < WS_NEEDED) return;

    char* ws = (char*)d_ws;
    float* wscp = (float*)(ws + 0);
    float* iscp = (float*)(ws + 4);
    float* maxp = (float*)(ws + WS_MAXP_OFF);
    double* partials = (double*)(ws + WS_PART_OFF);
    char* qw = ws + WS_QW_OFF;
    char* qx = ws + WS_QX_OFF;

    const long n_x = (long)in_sizes[0];   // 33554432
    const long n4_x = n_x >> 2;

    kprep<<<2112, 256, 0, stream>>>((const float4*)x, (const float4*)wt, maxp, partials, n4_x);
    kquant_w<<<256, 256, 0, stream>>>((const float4*)wt, (unsigned*)qw, partials, wscp);
    kquant_x<<<2048, 256, 0, stream>>>((const float4*)x, (unsigned*)qx, maxp, iscp, n4_x);

    const int grid = (MK_M / 256) * (MK_N / 256);  // 512
    kgemm<<<grid, 512, 0, stream>>>(qx, qw, bias, wscp, iscp, out);
}

// Round 11
// 103.685 us; speedup vs baseline: 2.9538x; 1.1012x over previous
//
#include <hip/hip_runtime.h>
#include <stdint.h>

// BitNetLinear eval forward on MI355X (gfx950).
// M = B*S = 32768, K = 1024 (in_features), N = 1024 (out_features).
//
// R10: fused quant-A + GEMM using the R2-PROVEN staging skeleton:
//   - B: global_load_lds -> triple-buffered LDS, pre-swizzled global source
//   - A: reg-staged fp32 x -> quantize -> ds_write, double-buffered LDS,
//     issued one full iteration ahead (T14 split; ~1500cyc latency cover)
//   - one raw barrier per K-tile; counted s_waitcnt vmcnt(2) lgkmcnt(0)
//     (queue = [B(kt) 2, A(kt+1) 4, B(kt+2) 2]; A-issue precedes B-issue)
// Deletes kquant_x (~25us) and the 64MB qx round-trip.
// Pipeline: kprep -> kquant_w -> kfused. Quant math bit-identical to R5-R8
// (reciprocal-mul, absmax 0.0); clamps dropped (|v*rin| <= 127+eps).

#define MK_M 32768
#define MK_K 1024
#define MK_N 1024

typedef __attribute__((ext_vector_type(4))) int int32x4;

// ---- workspace layout ----
#define WS_MAXP_OFF 64
#define WS_PART_OFF 8448
#define WS_QW_OFF 16384
#define WS_NEEDED (WS_QW_OFF + (1 << 20))

// fused: blocks [0,2048) -> per-block max|x|; blocks [2048,2112) -> partial sum|W|
__global__ void kprep(const float4* __restrict__ x4, const float4* __restrict__ w4,
                      float* __restrict__ maxp, double* __restrict__ partials, long n4x) {
    const int bid = blockIdx.x;
    if (bid < 2048) {
        float m = 0.f;
        const long stride = 2048L * 256;
        for (long i = (long)bid * 256 + threadIdx.x; i < n4x; i += stride) {
            float4 v = x4[i];
            m = fmaxf(m, fmaxf(fmaxf(fabsf(v.x), fabsf(v.y)), fmaxf(fabsf(v.z), fabsf(v.w))));
        }
        #pragma unroll
        for (int off = 1; off < 64; off <<= 1) m = fmaxf(m, __shfl_xor(m, off));
        __shared__ float sm[4];
        int lane = threadIdx.x & 63, wid = threadIdx.x >> 6;
        if (lane == 0) sm[wid] = m;
        __syncthreads();
        if (threadIdx.x == 0) maxp[bid] = fmaxf(fmaxf(sm[0], sm[1]), fmaxf(sm[2], sm[3]));
    } else {
        double s = 0.0;
        for (int i = (bid - 2048) * 256 + threadIdx.x; i < (1 << 18); i += 64 * 256) {
            float4 v = w4[i];
            s += (double)fabsf(v.x);
            s += (double)fabsf(v.y);
            s += (double)fabsf(v.z);
            s += (double)fabsf(v.w);
        }
        __shared__ double sd[256];
        sd[threadIdx.x] = s;
        __syncthreads();
        for (int h = 128; h > 0; h >>= 1) {
            if ((int)threadIdx.x < h) sd[threadIdx.x] += sd[threadIdx.x + h];
            __syncthreads();
        }
        if (threadIdx.x == 0) partials[bid - 2048] = sd[0];
    }
}

// every block redundantly reduces partials[64] in the SAME fixed order.
__global__ void kquant_w(const float4* __restrict__ w4, unsigned* __restrict__ qw,
                         const double* __restrict__ partials, float* __restrict__ wscp) {
    __shared__ double sws;
    if (threadIdx.x < 64) {
        double s = partials[threadIdx.x];
        #pragma unroll
        for (int off = 1; off < 64; off <<= 1) s += __shfl_xor(s, off);
        if (threadIdx.x == 0) sws = s;
    }
    __syncthreads();
    float wsc = (float)(sws / 1048576.0);   // mean|W| over 2^20 elements
    if (blockIdx.x == 0 && threadIdx.x == 0) *wscp = wsc;
    float thr = 0.5f * wsc;
    int stride = gridDim.x * blockDim.x;
    for (int i = blockIdx.x * blockDim.x + threadIdx.x; i < (1 << 18); i += stride) {
        float4 v = w4[i];
        int q0 = (fabsf(v.x) > thr) ? (v.x > 0.f ? 1 : -1) : 0;
        int q1 = (fabsf(v.y) > thr) ? (v.y > 0.f ? 1 : -1) : 0;
        int q2 = (fabsf(v.z) > thr) ? (v.z > 0.f ? 1 : -1) : 0;
        int q3 = (fabsf(v.w) > thr) ? (v.w > 0.f ? 1 : -1) : 0;
        qw[i] = (q0 & 0xff) | ((q1 & 0xff) << 8) | ((q2 & 0xff) << 16) | ((q3 & 0xff) << 24);
    }
}

// ---- fused quant-A + int8 GEMM ----
// Tile 128x256, BK=64, 8 waves (2Mx4N), wave = 64x64 (acc[4][4]).
// A: fp32 x -> 4x float4/thread (regs, issued 1 iter ahead) -> quantize ->
//    ds_write_b128 into As[2] (8KB each), XOR chunk swizzle (R2's).
// B: global_load_lds into Bs[3] (16KB each), pre-swizzled global source.
// One s_barrier per K-tile; vmcnt(2) lgkmcnt(0) at top (counted queue).
__global__ __launch_bounds__(512, 2) void kfused(
    const float* __restrict__ x, const char* __restrict__ qw,
    const float* __restrict__ bias, const float* __restrict__ wscp,
    const float* __restrict__ maxp, float* __restrict__ out)
{
    __shared__ __align__(16) char As[2][8192];
    __shared__ __align__(16) char Bs[3][16384];
    __shared__ float smx[8];

    const int t = threadIdx.x;
    const int l = t & 63;
    const int w = t >> 6;          // 0..7
    const int wm = w >> 2;         // 0..1
    const int wn = w & 3;          // 0..3

    // XCD-bijective swizzle: 1024 blocks, 8 XCDs, 128 contiguous per XCD.
    const int bid = blockIdx.x;
    const int wg = (bid & 7) * 128 + (bid >> 3);
    const int tm = wg >> 2, tn = wg & 3;
    const long m0 = (long)tm * 128;
    const int n0 = tn * 256;

    // i_scale: redundant deterministic reduce of maxp[2048]
    float m = 0.f;
    #pragma unroll
    for (int j = 0; j < 4; ++j) m = fmaxf(m, maxp[t + 512 * j]);
    #pragma unroll
    for (int off = 1; off < 64; off <<= 1) m = fmaxf(m, __shfl_xor(m, off));
    if (l == 0) smx[w] = m;
    __syncthreads();
    const float mm = fmaxf(fmaxf(fmaxf(smx[0], smx[1]), fmaxf(smx[2], smx[3])),
                           fmaxf(fmaxf(smx[4], smx[5]), fmaxf(smx[6], smx[7])));
    const float isc = mm / 127.0f;
    const float rin = 1.0f / isc;

    // A staging: thread t -> row arow = t>>2 (0..127), 16 floats at k-offset
    // (t&3)*16 within each 64-float K-window.
    const int arow = t >> 2;
    const int ac = t & 3;
    const float4* gA4 = (const float4*)(x + (m0 + arow) * MK_K + ac * 16);
    const int adsw = (ac ^ ((arow >> 1) & 3));          // swizzled chunk
    char* const adst0 = (char*)As[0] + arow * 64 + adsw * 16;
    char* const adst1 = (char*)As[1] + arow * 64 + adsw * 16;

    // B staging (R2 pattern): unit = 128 rows x 64B = 8KB = 512thr x 16B
    const int gch = (t & 3) ^ ((t >> 3) & 3);
    const char* gBt = qw + ((long)n0 + (t >> 2)) * MK_K + gch * 16;
    auto stageB = [&](int kt1, int b) {
        char* dst = (char*)Bs[b] + t * 16;
        const char* src = gBt + kt1 * 64;
        __builtin_amdgcn_global_load_lds(
            (const __attribute__((address_space(1))) void*)src,
            (__attribute__((address_space(3))) void*)dst, 16, 0, 0);
        __builtin_amdgcn_global_load_lds(
            (const __attribute__((address_space(1))) void*)(src + 128L * MK_K),
            (__attribute__((address_space(3))) void*)(dst + 8192), 16, 0, 0);
    };

    float4 ar0, ar1, ar2, ar3;   // in-flight A fp32 (16 VGPR)
    auto issueA = [&](int kt1) {
        ar0 = gA4[kt1 * 16 + 0];
        ar1 = gA4[kt1 * 16 + 1];
        ar2 = gA4[kt1 * 16 + 2];
        ar3 = gA4[kt1 * 16 + 3];
    };
    auto quantA = [&](char* dst) {
        int p[4];
        float4 vv[4] = {ar0, ar1, ar2, ar3};
        #pragma unroll
        for (int q = 0; q < 4; ++q) {
            int i0 = (int)rintf(vv[q].x * rin);
            int i1 = (int)rintf(vv[q].y * rin);
            int i2 = (int)rintf(vv[q].z * rin);
            int i3 = (int)rintf(vv[q].w * rin);
            p[q] = (i0 & 0xff) | ((i1 & 0xff) << 8) | ((i2 & 0xff) << 16) | ((i3 & 0xff) << 24);
        }
        int32x4 pk = {p[0], p[1], p[2], p[3]};
        *(int32x4*)dst = pk;
    };

    int32x4 acc[4][4];
    #pragma unroll
    for (int mi = 0; mi < 4; ++mi)
        #pragma unroll
        for (int ni = 0; ni < 4; ++ni) acc[mi][ni] = (int32x4)0;

    // prologue: queue must end as [B(0)2, A(1)4, B(1)2]
    issueA(0);                 // A(0) [4]
    stageB(0, 0);              // B(0) [2]
    asm volatile("s_waitcnt vmcnt(2)" ::: "memory");   // A(0) done
    quantA(adst0);             // As[0] = A(0)
    issueA(1);                 // A(1) [4]
    stageB(1, 1);              // B(1) [2]

    for (int kt = 0; kt < 16; ++kt) {
        if (kt < 15) asm volatile("s_waitcnt vmcnt(2) lgkmcnt(0)" ::: "memory");
        else         asm volatile("s_waitcnt vmcnt(0) lgkmcnt(0)" ::: "memory");
        __builtin_amdgcn_s_barrier();

        if (kt < 15) quantA((kt & 1) ? adst0 : adst1);  // write A(kt+1) -> As[(kt+1)&1]
        if (kt < 14) {
            issueA(kt + 2);                              // A first (queue order!)
            stageB(kt + 2, (kt + 2) % 3);                // then B
        }

        const char* bufA = As[kt & 1];
        const char* bufB = Bs[kt % 3];
        int32x4 af[4], bf[4];
        #pragma unroll
        for (int i = 0; i < 4; ++i) {
            int row = wm * 64 + i * 16 + (l & 15);
            int ch = (l >> 4) ^ ((row >> 1) & 3);
            af[i] = *(const int32x4*)(bufA + row * 64 + ch * 16);
        }
        #pragma unroll
        for (int i = 0; i < 4; ++i) {
            int row = wn * 64 + i * 16 + (l & 15);
            int ch = (l >> 4) ^ ((row >> 1) & 3);
            bf[i] = *(const int32x4*)(bufB + row * 64 + ch * 16);
        }
        __builtin_amdgcn_s_setprio(1);
        #pragma unroll
        for (int mi = 0; mi < 4; ++mi)
            #pragma unroll
            for (int ni = 0; ni < 4; ++ni)
                acc[mi][ni] = __builtin_amdgcn_mfma_i32_16x16x64_i8(
                    af[mi], bf[ni], acc[mi][ni], 0, 0, 0);
        __builtin_amdgcn_s_setprio(0);
    }

    // epilogue: C/D layout col = lane&15, row = (lane>>4)*4 + reg (verified)
    const float wsc = *wscp;
    const int crow = (l >> 4) * 4;
    const int ccol = l & 15;
    #pragma unroll
    for (int mi = 0; mi < 4; ++mi) {
        #pragma unroll
        for (int ni = 0; ni < 4; ++ni) {
            long r0 = m0 + wm * 64 + mi * 16 + crow;
            int c = n0 + wn * 64 + ni * 16 + ccol;
            float b = bias[c];
            #pragma unroll
            for (int j = 0; j < 4; ++j) {
                out[(r0 + j) * MK_N + c] = ((float)acc[mi][ni][j] * wsc) * isc + b;
            }
        }
    }
}

extern "C" void kernel_launch(void* const* d_in, const int* in_sizes, int n_in,
                              void* d_out, int out_size, void* d_ws, size_t ws_size,
                              hipStream_t stream) {
    const float* x = (const float*)d_in[0];
    const float* wt = (const float*)d_in[1];
    const float* bias = (const float*)d_in[2];
    float* out = (float*)d_out;

    if (ws_size < WS_NEEDED) return;

    char* ws = (char*)d_ws;
    float* wscp = (float*)(ws + 0);
    float* maxp = (float*)(ws + WS_MAXP_OFF);
    double* partials = (double*)(ws + WS_PART_OFF);
    char* qw = ws + WS_QW_OFF;

    const long n_x = (long)in_sizes[0];   // 33554432
    const long n4_x = n_x >> 2;

    kprep<<<2112, 256, 0, stream>>>((const float4*)x, (const float4*)wt, maxp, partials, n4_x);
    kquant_w<<<256, 256, 0, stream>>>((const float4*)wt, (unsigned*)qw, partials, wscp);

    const int grid = (MK_M / 128) * (MK_N / 256);  // 1024
    kfused<<<grid, 512, 0, stream>>>(x, qw, bias, wscp, maxp, out);
}